// Round 18
// baseline (85.565 us; speedup 1.0000x reference)
//
#include <hip/hip_runtime.h>
#include <hip/hip_bf16.h>
#include <stdint.h>

using f32x4  = __attribute__((ext_vector_type(4))) float;
using bf16x8 = __attribute__((ext_vector_type(8))) short;
using short4v = __attribute__((ext_vector_type(4))) short;

#define DEVINL static __device__ __forceinline__

DEVINL short f2bf(float f) {
    union { float f; uint32_t u; } v; v.f = f;
    uint32_t r = (v.u + 0x7FFFu + ((v.u >> 16) & 1u)) >> 16;   // RNE
    return (short)(uint16_t)r;
}
DEVINL float bf2f(short s) {
    union { uint32_t u; float f; } v; v.u = ((uint32_t)(uint16_t)s) << 16;
    return v.f;
}
DEVINL float fexp2(float x) {
    float r;
    asm("v_exp_f32 %0, %1" : "=v"(r) : "v"(x));
    return r;
}
DEVINL uint32_t pk2bf(float a, float b) {
    union { __hip_bfloat162 v; uint32_t u; } c;
    c.v = __float22bfloat162_rn(float2{a, b});
    return c.u;
}

// async global -> LDS, 16B per lane. LDS dest is wave-uniform base + lane*16 (HW).
DEVINL void gld16(const short* g, short* l) {
    __builtin_amdgcn_global_load_lds(
        (const __attribute__((address_space(1))) unsigned int*)g,
        (__attribute__((address_space(3))) unsigned int*)l, 16, 0, 0);
}

#define LOG2E 1.44269504f

// ---------------- K0: weight prep (fp32 -> bf16, stack Wg|Wt|Wp) ----------
__global__ __launch_bounds__(256) void k0_prep(
        const float* __restrict__ Wg, const float* __restrict__ Wt, const float* __restrict__ Wp,
        const float* __restrict__ bg, const float* __restrict__ bt, const float* __restrict__ bp,
        const float* __restrict__ Ww,
        short* __restrict__ W_all, short* __restrict__ Ww16, float* __restrict__ b_all) {
    int i = blockIdx.x * 256 + threadIdx.x;
    if (i < 384 * 256) {
        int r = i >> 8, c = i & 255;
        float v = (r < 128) ? Wg[r * 256 + c]
                : (r < 256) ? Wt[(r - 128) * 256 + c] * LOG2E
                            : Wp[(r - 256) * 256 + c];
        W_all[i] = f2bf(v);
    } else if (i < 384 * 256 + 256 * 128) {
        int j = i - 384 * 256;
        Ww16[j] = f2bf(Ww[j]);
    }
    if (i < 384) {
        b_all[i] = (i < 128) ? bg[i] : (i < 256) ? bt[i - 128] * LOG2E : bp[i - 256];
    }
}

// ---------------- K1: fused conv1x1 x3 GEMM, single x read, 3 otiles per block ----------
__global__ __launch_bounds__(256) void k1_conv(const float* __restrict__ x,
        const short* __restrict__ W_all, const float* __restrict__ b_all,
        short* __restrict__ OutT, short* __restrict__ Kmat, short* __restrict__ Vmat) {
    __shared__ short xs[128 * 32];
    __shared__ short obuf[128 * 128];
    const int ntile = blockIdx.x;           // 32
    const int b     = blockIdx.y;           // 8
    const int tid  = threadIdx.x;
    const int lane = tid & 63;
    const int wave = tid >> 6;
    const int wn = wave >> 1, wo = wave & 1;
    const int l15 = lane & 15, lh = lane >> 4;

    f32x4 acc[3][4][4];
    #pragma unroll
    for (int ot = 0; ot < 3; ot++)
        #pragma unroll
        for (int i = 0; i < 4; i++)
            #pragma unroll
            for (int j = 0; j < 4; j++) acc[ot][i][j] = f32x4{0.f, 0.f, 0.f, 0.f};

    const int n0 = ntile * 128;
    const float* xb = x + (size_t)b * 256 * 4096;

    const int srow_base = (lane & 15) + wave * 16;
    const int sc0 = (lane >> 4) * 8;

    for (int kt = 0; kt < 8; kt++) {
        __syncthreads();
        #pragma unroll
        for (int p = 0; p < 2; p++) {
            int row = srow_base + p * 64;
            const float* xp = xb + (size_t)(kt * 32 + sc0) * 4096 + n0 + row;
            bf16x8 w8;
            #pragma unroll
            for (int j = 0; j < 8; j++) w8[j] = f2bf(xp[(size_t)j * 4096]);
            int ch = (sc0 >> 3) ^ ((row >> 1) & 3);
            *(bf16x8*)&xs[row * 32 + ch * 8] = w8;
        }
        __syncthreads();

        bf16x8 a[4];
        #pragma unroll
        for (int nf = 0; nf < 4; nf++) {
            int row = wn * 64 + nf * 16 + l15;
            int ch  = lh ^ ((row >> 1) & 3);
            a[nf] = *(const bf16x8*)&xs[row * 32 + ch * 8];
        }
        #pragma unroll
        for (int ot = 0; ot < 3; ot++) {
            bf16x8 w[4];
            #pragma unroll
            for (int of = 0; of < 4; of++)
                w[of] = *(const bf16x8*)(W_all + (size_t)(ot * 128 + wo * 64 + of * 16 + l15) * 256 + kt * 32 + lh * 8);
            #pragma unroll
            for (int nf = 0; nf < 4; nf++)
                #pragma unroll
                for (int of = 0; of < 4; of++)
                    acc[ot][nf][of] = __builtin_amdgcn_mfma_f32_16x16x32_bf16(a[nf], w[of], acc[ot][nf][of], 0, 0, 0);
        }
    }

    #pragma unroll
    for (int ot = 0; ot < 3; ot++) {
        __syncthreads();
        #pragma unroll
        for (int of = 0; of < 4; of++) {
            int ocol = wo * 64 + of * 16 + l15;
            float bias = b_all[ot * 128 + ocol];
            #pragma unroll
            for (int nf = 0; nf < 4; nf++)
                #pragma unroll
                for (int r = 0; r < 4; r++) {
                    int n  = wn * 64 + nf * 16 + lh * 4 + r;
                    int ch = (ocol >> 3) ^ (n & 15);
                    obuf[n * 128 + ch * 8 + (ocol & 7)] = f2bf(acc[ot][nf][of][r] + bias);
                }
        }
        __syncthreads();

        if (ot == 1) {
            #pragma unroll
            for (int p = 0; p < 8; p++) {
                int n  = wave * 4 + lh + p * 16;
                int ch = l15 ^ (n & 15);
                bf16x8 v = *(const bf16x8*)&obuf[n * 128 + ch * 8];
                *(bf16x8*)(OutT + ((size_t)b * 4096 + n0 + n) * 128 + l15 * 8) = v;
            }
        } else if (ot == 2) {
            const int wp = tid >> 3;
            const int cc = (tid & 7) * 16;
            short* kdst = Kmat + ((size_t)b * 1024 + ntile * 32 + wp) * 128 + cc;
            #pragma unroll
            for (int cblk = 0; cblk < 2; cblk++) {
                const int chunk = (cc >> 3) + cblk;
                float mx[8];
                #pragma unroll
                for (int j = 0; j < 8; j++) mx[j] = -1e30f;
                #pragma unroll
                for (int q4 = 0; q4 < 4; q4++) {
                    int n = (q4 >> 1) * 64 + 2 * wp + (q4 & 1);
                    bf16x8 v = *(const bf16x8*)&obuf[n * 128 + ((chunk ^ (n & 15)) * 8)];
                    #pragma unroll
                    for (int j = 0; j < 8; j++) mx[j] = fmaxf(mx[j], bf2f(v[j]));
                }
                bf16x8 vo;
                #pragma unroll
                for (int j = 0; j < 8; j++) vo[j] = f2bf(mx[j]);
                *(bf16x8*)(kdst + cblk * 8) = vo;
            }
        } else {
            const int c   = tid >> 1;
            const int wp0 = (tid & 1) * 16;
            const int chb = c >> 3, cl = c & 7;
            #pragma unroll
            for (int half = 0; half < 2; half++) {
                bf16x8 vo;
                #pragma unroll
                for (int j = 0; j < 8; j++) {
                    int wp = wp0 + half * 8 + j;
                    float mx = -1e30f;
                    #pragma unroll
                    for (int q4 = 0; q4 < 4; q4++) {
                        int n = (q4 >> 1) * 64 + 2 * wp + (q4 & 1);
                        mx = fmaxf(mx, bf2f(obuf[n * 128 + ((chb ^ (n & 15)) * 8) + cl]));
                    }
                    vo[j] = f2bf(mx);
                }
                *(bf16x8*)(Vmat + ((size_t)b * 128 + c) * 1024 + ntile * 32 + wp0 + half * 8) = vo;
            }
        }
    }
}

// ---------------- K3: flash attention, 8 waves x 32 q-rows, m-split 2, P in dead-K ----
// waves 0-3: m in [0,512); waves 4-7: m in [512,1024); each wave 32 q-rows (2 nf blocks).
// Per half: dbuf K[64x128] + V[128x64] tiles (m-tile 64). 128KB LDS, 1 block/CU, 2 w/SIMD.
__global__ __launch_bounds__(512) void k3_attn(const short* __restrict__ OutT,
        const short* __restrict__ Kmat, const short* __restrict__ Vmat,
        const short* __restrict__ Ww16, const float* __restrict__ bw,
        short* __restrict__ wy) {
    __shared__ short smem[65536];       // 128 KB
    const int bid = blockIdx.x;         // 256
    const int b   = bid & 7;
    const int nt  = bid >> 3;           // 32 tiles of 128 rows
    const int tid = threadIdx.x;
    const int lane = tid & 63;
    const int wave = tid >> 6;          // 0..7
    const int half = wave >> 2;
    const int wl   = wave & 3;
    const int l15 = lane & 15, lh = lane >> 4;
    const int nblk = nt * 128;
    const int n0 = nblk + wl * 32;
    const int mbase = half * 512;

    const short* Kb = Kmat + (size_t)b * 1024 * 128;
    const short* Vb = Vmat + (size_t)b * 128 * 1024;
    short* const sKh = smem + half * 16384;           // [2 dbuf][64*128]
    short* const sVh = smem + 32768 + half * 16384;   // [2 dbuf][128*64]

    auto STAGE = [&](int t, int bufi) {
        const int m0 = mbase + t * 64;
        #pragma unroll
        for (int i = 0; i < 4; i++) {
            const int segb = (i * 4 + wl) * 64;       // chunk units, wave-uniform
            const int rowK = (segb >> 4) + (lane >> 4);
            const int chkK = lane & 15;
            gld16(Kb + (size_t)(m0 + rowK) * 128 + ((chkK ^ (rowK & 15)) << 3),
                  sKh + bufi * 8192 + segb * 8);
            const int rowV = (segb >> 3) + (lane >> 3);
            const int chkV = lane & 7;
            gld16(Vb + (size_t)rowV * 1024 + m0 + ((chkV ^ (rowV & 7)) << 3),
                  sVh + bufi * 8192 + segb * 8);
        }
    };

    bf16x8 q[2][4];
    #pragma unroll
    for (int nf = 0; nf < 2; nf++) {
        const short* qrow = OutT + ((size_t)b * 4096 + n0 + nf * 16 + l15) * 128;
        #pragma unroll
        for (int ks = 0; ks < 4; ks++)
            q[nf][ks] = *(const bf16x8*)(qrow + ks * 32 + lh * 8);
    }

    f32x4 y[2][8];
    #pragma unroll
    for (int nf = 0; nf < 2; nf++)
        #pragma unroll
        for (int cf = 0; cf < 8; cf++) y[nf][cf] = f32x4{0.f, 0.f, 0.f, 0.f};
    float mrun[2] = { -1e30f, -1e30f }, lrun[2] = { 0.f, 0.f };   // per-lane q = l15; base-2

    STAGE(0, 0);
    int cur = 0;

    for (int t = 0; t < 8; t++) {
        if (t < 7) {
            STAGE(t + 1, cur ^ 1);
            asm volatile("s_waitcnt vmcnt(8)" ::: "memory");
        } else {
            asm volatile("s_waitcnt vmcnt(0)" ::: "memory");
        }
        __builtin_amdgcn_s_barrier();
        __builtin_amdgcn_sched_barrier(0);

        const short* cK = sKh + cur * 8192;
        const short* cV = sVh + cur * 8192;

        // S^T = K Q^T: lane q = l15 (per nf block), m = mf*16 + lh*4 + r
        f32x4 S[2][4];
        #pragma unroll
        for (int nf = 0; nf < 2; nf++)
            #pragma unroll
            for (int mf = 0; mf < 4; mf++) S[nf][mf] = f32x4{0.f, 0.f, 0.f, 0.f};
        #pragma unroll
        for (int ks = 0; ks < 4; ks++) {
            bf16x8 kf[4];
            #pragma unroll
            for (int mf = 0; mf < 4; mf++) {
                int mrow = mf * 16 + l15;
                int jj   = ks * 4 + lh;
                kf[mf] = *(const bf16x8*)&cK[mrow * 128 + ((jj ^ (mrow & 15)) << 3)];
            }
            __builtin_amdgcn_s_setprio(1);
            #pragma unroll
            for (int nf = 0; nf < 2; nf++)
                #pragma unroll
                for (int mf = 0; mf < 4; mf++)
                    S[nf][mf] = __builtin_amdgcn_mfma_f32_16x16x32_bf16(kf[mf], q[nf][ks], S[nf][mf], 0, 0, 0);
            __builtin_amdgcn_s_setprio(0);
        }

        // lane-local softmax per nf (base 2)
        float pm[2];
        #pragma unroll
        for (int nf = 0; nf < 2; nf++) {
            float v = S[nf][0][0];
            #pragma unroll
            for (int mf = 0; mf < 4; mf++)
                #pragma unroll
                for (int r = 0; r < 4; r++) v = fmaxf(v, S[nf][mf][r]);
            v = fmaxf(v, __shfl_xor(v, 16));
            v = fmaxf(v, __shfl_xor(v, 32));
            pm[nf] = v;
        }
        bool grow = (pm[0] > mrun[0] + 8.656f) | (pm[1] > mrun[1] + 8.656f);
        if (__any(grow)) {
            #pragma unroll
            for (int nf = 0; nf < 2; nf++) {
                float mnew  = fmaxf(mrun[nf], pm[nf]);
                float alpha = fexp2(mrun[nf] - mnew);
                mrun[nf] = mnew;
                lrun[nf] *= alpha;
                float aR[4];
                #pragma unroll
                for (int r = 0; r < 4; r++) aR[r] = __shfl(alpha, lh * 4 + r);
                #pragma unroll
                for (int cf = 0; cf < 8; cf++)
                    #pragma unroll
                    for (int r = 0; r < 4; r++) y[nf][cf][r] *= aR[r];
            }
        }
        #pragma unroll
        for (int nf = 0; nf < 2; nf++) {
            float rs = 0.f;
            #pragma unroll
            for (int mf = 0; mf < 4; mf++)
                #pragma unroll
                for (int r = 0; r < 4; r++) {
                    float p = fexp2(S[nf][mf][r] - mrun[nf]);
                    S[nf][mf][r] = p;
                    rs += p;
                }
            rs += __shfl_xor(rs, 16);
            rs += __shfl_xor(rs, 32);
            lrun[nf] += rs;
        }

        // barrier: all waves' cK reads complete before P overwrites the dead K buffer
        __builtin_amdgcn_sched_barrier(0);
        __builtin_amdgcn_s_barrier();

        // P -> dead-K region, per-wave [32 rows][64 m], 8B-granule XOR swizzle
        short* const sPw = sKh + cur * 8192 + wl * 2048;
        #pragma unroll
        for (int nf = 0; nf < 2; nf++)
            #pragma unroll
            for (int mf = 0; mf < 4; mf++) {
                uint2 pk = { pk2bf(S[nf][mf][0], S[nf][mf][1]), pk2bf(S[nf][mf][2], S[nf][mf][3]) };
                int row = nf * 16 + l15;
                *(uint2*)&sPw[(row << 6) + (((mf * 4 + lh) ^ l15) << 2)] = pk;
            }

        // y += P @ V^T (vf shared across both nf)
        #pragma unroll
        for (int ks2 = 0; ks2 < 2; ks2++) {
            int u0 = ks2 * 8 + lh * 2;
            bf16x8 pa[2];
            #pragma unroll
            for (int nf = 0; nf < 2; nf++) {
                int row = nf * 16 + l15;
                short4v lo = *(const short4v*)&sPw[(row << 6) + (((u0)     ^ l15) << 2)];
                short4v hi = *(const short4v*)&sPw[(row << 6) + (((u0 + 1) ^ l15) << 2)];
                pa[nf] = bf16x8{ lo.x, lo.y, lo.z, lo.w, hi.x, hi.y, hi.z, hi.w };
            }
            int jj = ks2 * 4 + lh;
            __builtin_amdgcn_s_setprio(1);
            #pragma unroll
            for (int cf = 0; cf < 8; cf++) {
                int crow = cf * 16 + l15;
                bf16x8 vf = *(const bf16x8*)&cV[crow * 64 + ((jj ^ (crow & 7)) << 3)];
                #pragma unroll
                for (int nf = 0; nf < 2; nf++)
                    y[nf][cf] = __builtin_amdgcn_mfma_f32_16x16x32_bf16(pa[nf], vf, y[nf][cf], 0, 0, 0);
            }
            __builtin_amdgcn_s_setprio(0);
        }

        __builtin_amdgcn_sched_barrier(0);
        __builtin_amdgcn_s_barrier();       // protect cur buffers before next-iter overwrite
        cur ^= 1;
    }

    // ---- merge halves (online-softmax split-K merge, R13-verified pattern) ----
    float* const fsm = (float*)smem;                  // [128 rows][132]
    float* const fl  = fsm + 128 * 132;               // [128] lrun
    float* const fm  = fl + 128;                      // [128] mrun
    if (half == 1) {
        #pragma unroll
        for (int nf = 0; nf < 2; nf++) {
            #pragma unroll
            for (int cf = 0; cf < 8; cf++)
                #pragma unroll
                for (int r = 0; r < 4; r++)
                    fsm[(wl * 32 + nf * 16 + lh * 4 + r) * 132 + cf * 16 + l15] = y[nf][cf][r];
            if (lh == 0) {
                fl[wl * 32 + nf * 16 + l15] = lrun[nf];
                fm[wl * 32 + nf * 16 + l15] = mrun[nf];
            }
        }
    }
    __syncthreads();
    if (half == 0) {
        #pragma unroll
        for (int nf = 0; nf < 2; nf++) {
            float m1 = fm[wl * 32 + nf * 16 + l15];
            float l1 = fl[wl * 32 + nf * 16 + l15];
            float mnew = fmaxf(mrun[nf], m1);
            float a0 = fexp2(mrun[nf] - mnew);
            float a1 = fexp2(m1 - mnew);
            float lnew = lrun[nf] * a0 + l1 * a1;
            float aR0[4], aR1[4], li[4];
            #pragma unroll
            for (int r = 0; r < 4; r++) {
                aR0[r] = __shfl(a0, lh * 4 + r);
                aR1[r] = __shfl(a1, lh * 4 + r);
                li[r]  = 1.f / __shfl(lnew, lh * 4 + r);
            }
            #pragma unroll
            for (int cf = 0; cf < 8; cf++)
                #pragma unroll
                for (int r = 0; r < 4; r++) {
                    float y1 = fsm[(wl * 32 + nf * 16 + lh * 4 + r) * 132 + cf * 16 + l15];
                    y[nf][cf][r] = (y[nf][cf][r] * aR0[r] + y1 * aR1[r]) * li[r];
                }
        }
    }
    __syncthreads();    // fsm dead before Yt overwrite

    // ---- epilogue per 64-row half: Yt bounce + Ww GEMM (o-split 32 per wave) ----
    short* const Yt = smem;                           // [64 n][128 c], XOR-swizzled
    #pragma unroll
    for (int h = 0; h < 2; h++) {
        if (h) __syncthreads();                       // protect Yt reuse
        if (half == 0 && (wl >> 1) == h) {            // waves 2h, 2h+1 own this half
            #pragma unroll
            for (int nf = 0; nf < 2; nf++)
                #pragma unroll
                for (int cf = 0; cf < 8; cf++) {
                    int c = cf * 16 + l15;
                    #pragma unroll
                    for (int r = 0; r < 4; r++) {
                        int n = (wl & 1) * 32 + nf * 16 + lh * 4 + r;
                        Yt[n * 128 + (((c >> 3) ^ (n & 15)) << 3) + (c & 7)] = f2bf(y[nf][cf][r]);
                    }
                }
        }
        __syncthreads();

        bf16x8 by[4][4];
        #pragma unroll
        for (int nfi = 0; nfi < 4; nfi++)
            #pragma unroll
            for (int ks = 0; ks < 4; ks++) {
                int n  = nfi * 16 + l15;
                int kc = ks * 4 + lh;
                by[nfi][ks] = *(const bf16x8*)&Yt[n * 128 + ((kc ^ (n & 15)) << 3)];
            }

        short* const sOut = smem + 8192 + wave * 2304;   // [32 o][72]
        const int obase = wave * 32;
        #pragma unroll
        for (int of = 0; of < 2; of++) {
            bf16x8 aw[4];
            #pragma unroll
            for (int ks = 0; ks < 4; ks++)
                aw[ks] = *(const bf16x8*)(Ww16 + (size_t)(obase + of * 16 + l15) * 128 + ks * 32 + lh * 8);
            #pragma unroll
            for (int nfi = 0; nfi < 4; nfi++) {
                f32x4 acc = f32x4{0.f, 0.f, 0.f, 0.f};
                #pragma unroll
                for (int ks = 0; ks < 4; ks++)
                    acc = __builtin_amdgcn_mfma_f32_16x16x32_bf16(aw[ks], by[nfi][ks], acc, 0, 0, 0);
                #pragma unroll
                for (int r = 0; r < 4; r++) {
                    int o_loc = of * 16 + lh * 4 + r;
                    sOut[o_loc * 72 + nfi * 16 + l15] = f2bf(acc[r] + bw[obase + o_loc]);
                }
            }
        }

        #pragma unroll
        for (int p = 0; p < 4; p++) {
            int o_loc = p * 8 + (lane >> 3);
            int n8    = (lane & 7) * 8;
            bf16x8 v = *(const bf16x8*)&sOut[o_loc * 72 + n8];
            *(bf16x8*)(wy + ((size_t)b * 256 + obase + o_loc) * 4096 + nblk + h * 64 + n8) = v;
        }
    }
}

// ---------------- K45: BN stats + apply + residual + global spatial max ----------------
__global__ __launch_bounds__(512) void k45_bnmax(const short* __restrict__ wy,
        const float* __restrict__ x,
        const float* __restrict__ gamma, const float* __restrict__ beta,
        float* __restrict__ outp) {
    const int o   = blockIdx.x;     // 256
    const int tid = threadIdx.x;    // 512
    const int lane = tid & 63;
    const int wave = tid >> 6;

    bf16x8 w8[8];
    float s = 0.f, s2 = 0.f;
    #pragma unroll
    for (int b = 0; b < 8; b++) {
        w8[b] = *(const bf16x8*)(wy + ((size_t)b * 256 + o) * 4096 + tid * 8);
        #pragma unroll
        for (int j = 0; j < 8; j++) {
            float f = bf2f(w8[b][j]);
            s += f; s2 += f * f;
        }
    }
    #pragma unroll
    for (int off = 1; off < 64; off <<= 1) { s += __shfl_xor(s, off); s2 += __shfl_xor(s2, off); }
    __shared__ float sred[8][2];
    if (lane == 0) { sred[wave][0] = s; sred[wave][1] = s2; }
    __syncthreads();
    s = 0.f; s2 = 0.f;
    #pragma unroll
    for (int wv = 0; wv < 8; wv++) { s += sred[wv][0]; s2 += sred[wv][1]; }
    float mean = s * (1.f / 32768.f);
    float var  = s2 * (1.f / 32768.f) - mean * mean;
    float rstd = rsqrtf(var + 1e-5f);
    float A = rstd * gamma[o];
    float B = beta[o] - mean * A;

    float mx[8];
    #pragma unroll
    for (int b = 0; b < 8; b++) {
        const float* px = x + ((size_t)b * 256 + o) * 4096 + tid * 8;
        float4 xa = *(const float4*)px;
        float4 xb = *(const float4*)(px + 4);
        float m = bf2f(w8[b][0]) * A + B + xa.x;
        m = fmaxf(m, bf2f(w8[b][1]) * A + B + xa.y);
        m = fmaxf(m, bf2f(w8[b][2]) * A + B + xa.z);
        m = fmaxf(m, bf2f(w8[b][3]) * A + B + xa.w);
        m = fmaxf(m, bf2f(w8[b][4]) * A + B + xb.x);
        m = fmaxf(m, bf2f(w8[b][5]) * A + B + xb.y);
        m = fmaxf(m, bf2f(w8[b][6]) * A + B + xb.z);
        m = fmaxf(m, bf2f(w8[b][7]) * A + B + xb.w);
        mx[b] = m;
    }
    #pragma unroll
    for (int b = 0; b < 8; b++)
        #pragma unroll
        for (int off = 1; off < 64; off <<= 1) mx[b] = fmaxf(mx[b], __shfl_xor(mx[b], off));
    __shared__ float mred[8][8];
    if (lane == 0) {
        #pragma unroll
        for (int b = 0; b < 8; b++) mred[wave][b] = mx[b];
    }
    __syncthreads();
    if (tid < 8) {
        float m = mred[0][tid];
        #pragma unroll
        for (int wv = 1; wv < 8; wv++) m = fmaxf(m, mred[wv][tid]);
        outp[tid * 256 + o] = m;
    }
}

extern "C" void kernel_launch(void* const* d_in, const int* in_sizes, int n_in,
                              void* d_out, int out_size, void* d_ws, size_t ws_size,
                              hipStream_t stream) {
    const float* x     = (const float*)d_in[0];
    const float* Wg    = (const float*)d_in[1];
    const float* bg    = (const float*)d_in[2];
    const float* Wt    = (const float*)d_in[3];
    const float* bt    = (const float*)d_in[4];
    const float* Wp    = (const float*)d_in[5];
    const float* bp    = (const float*)d_in[6];
    const float* Ww    = (const float*)d_in[7];
    const float* bw    = (const float*)d_in[8];
    const float* gamma = (const float*)d_in[9];
    const float* beta  = (const float*)d_in[10];
    float* outp = (float*)d_out;

    char* ws = (char*)d_ws;
    size_t off = 0;
    auto alloc = [&](size_t bytes) -> void* {
        void* p = ws + off;
        off = (off + bytes + 255) & ~(size_t)255;
        return p;
    };
    short* W_all = (short*)alloc((size_t)384 * 256 * 2);
    short* Ww16  = (short*)alloc((size_t)256 * 128 * 2);
    float* b_all = (float*)alloc((size_t)384 * 4);
    short* OutT  = (short*)alloc((size_t)8 * 4096 * 128 * 2);
    short* Kmat  = (short*)alloc((size_t)8 * 1024 * 128 * 2);
    short* Vmat  = (short*)alloc((size_t)8 * 128 * 1024 * 2);
    short* wy    = (short*)alloc((size_t)8 * 256 * 4096 * 2);

    k0_prep<<<512, 256, 0, stream>>>(Wg, Wt, Wp, bg, bt, bp, Ww, W_all, Ww16, b_all);
    k1_conv<<<dim3(32, 8), 256, 0, stream>>>(x, W_all, b_all, OutT, Kmat, Vmat);
    k3_attn<<<256, 512, 0, stream>>>(OutT, Kmat, Vmat, Ww16, bw, wy);
    k45_bnmax<<<256, 512, 0, stream>>>(wy, x, gamma, beta, outp);
}

// Round 19
// 81.317 us; speedup vs baseline: 1.0522x; 1.0522x over previous
//
#include <hip/hip_runtime.h>
#include <hip/hip_bf16.h>
#include <stdint.h>

using f32x4  = __attribute__((ext_vector_type(4))) float;
using bf16x8 = __attribute__((ext_vector_type(8))) short;
using short4v = __attribute__((ext_vector_type(4))) short;

#define DEVINL static __device__ __forceinline__

DEVINL short f2bf(float f) {
    union { float f; uint32_t u; } v; v.f = f;
    uint32_t r = (v.u + 0x7FFFu + ((v.u >> 16) & 1u)) >> 16;   // RNE
    return (short)(uint16_t)r;
}
DEVINL float bf2f(short s) {
    union { uint32_t u; float f; } v; v.u = ((uint32_t)(uint16_t)s) << 16;
    return v.f;
}
DEVINL float fexp2(float x) {
    float r;
    asm("v_exp_f32 %0, %1" : "=v"(r) : "v"(x));
    return r;
}
DEVINL uint32_t pk2bf(float a, float b) {
    union { __hip_bfloat162 v; uint32_t u; } c;
    c.v = __float22bfloat162_rn(float2{a, b});
    return c.u;
}

// async global -> LDS, 16B per lane. LDS dest is wave-uniform base + lane*16 (HW).
DEVINL void gld16(const short* g, short* l) {
    __builtin_amdgcn_global_load_lds(
        (const __attribute__((address_space(1))) unsigned int*)g,
        (__attribute__((address_space(3))) unsigned int*)l, 16, 0, 0);
}

#define LOG2E 1.44269504f

// ---------------- K0: weight prep (fp32 -> bf16, stack Wg|Wt|Wp) ----------
__global__ __launch_bounds__(256) void k0_prep(
        const float* __restrict__ Wg, const float* __restrict__ Wt, const float* __restrict__ Wp,
        const float* __restrict__ bg, const float* __restrict__ bt, const float* __restrict__ bp,
        const float* __restrict__ Ww,
        short* __restrict__ W_all, short* __restrict__ Ww16, float* __restrict__ b_all) {
    int i = blockIdx.x * 256 + threadIdx.x;
    if (i < 384 * 256) {
        int r = i >> 8, c = i & 255;
        float v = (r < 128) ? Wg[r * 256 + c]
                : (r < 256) ? Wt[(r - 128) * 256 + c] * LOG2E
                            : Wp[(r - 256) * 256 + c];
        W_all[i] = f2bf(v);
    } else if (i < 384 * 256 + 256 * 128) {
        int j = i - 384 * 256;
        Ww16[j] = f2bf(Ww[j]);
    }
    if (i < 384) {
        b_all[i] = (i < 128) ? bg[i] : (i < 256) ? bt[i - 128] * LOG2E : bp[i - 256];
    }
}

// ---------------- K1: fused conv1x1 x3 GEMM, single x read, xs double-buffered ----------
__global__ __launch_bounds__(256) void k1_conv(const float* __restrict__ x,
        const short* __restrict__ W_all, const float* __restrict__ b_all,
        short* __restrict__ OutT, short* __restrict__ Kmat, short* __restrict__ Vmat) {
    __shared__ short xs[2][128 * 32];    // dbuf [n][c], 16B-chunk XOR swizzle: ch ^= (n>>1)&3
    __shared__ short obuf[128 * 128];
    const int ntile = blockIdx.x;           // 32
    const int b     = blockIdx.y;           // 8
    const int tid  = threadIdx.x;
    const int lane = tid & 63;
    const int wave = tid >> 6;
    const int wn = wave >> 1, wo = wave & 1;
    const int l15 = lane & 15, lh = lane >> 4;

    f32x4 acc[3][4][4];
    #pragma unroll
    for (int ot = 0; ot < 3; ot++)
        #pragma unroll
        for (int i = 0; i < 4; i++)
            #pragma unroll
            for (int j = 0; j < 4; j++) acc[ot][i][j] = f32x4{0.f, 0.f, 0.f, 0.f};

    const int n0 = ntile * 128;
    const float* xb = x + (size_t)b * 256 * 4096;

    const int srow_base = (lane & 15) + wave * 16;
    const int sc0 = (lane >> 4) * 8;

    auto STAGE = [&](int kt, int bufi) {
        #pragma unroll
        for (int p = 0; p < 2; p++) {
            int row = srow_base + p * 64;
            const float* xp = xb + (size_t)(kt * 32 + sc0) * 4096 + n0 + row;
            bf16x8 w8;
            #pragma unroll
            for (int j = 0; j < 8; j++) w8[j] = f2bf(xp[(size_t)j * 4096]);
            int ch = (sc0 >> 3) ^ ((row >> 1) & 3);
            *(bf16x8*)&xs[bufi][row * 32 + ch * 8] = w8;
        }
    };

    STAGE(0, 0);
    __syncthreads();
    int cur = 0;

    for (int kt = 0; kt < 8; kt++) {
        if (kt < 7) STAGE(kt + 1, cur ^ 1);

        bf16x8 a[4];
        #pragma unroll
        for (int nf = 0; nf < 4; nf++) {
            int row = wn * 64 + nf * 16 + l15;
            int ch  = lh ^ ((row >> 1) & 3);
            a[nf] = *(const bf16x8*)&xs[cur][row * 32 + ch * 8];
        }
        #pragma unroll
        for (int ot = 0; ot < 3; ot++) {
            bf16x8 w[4];
            #pragma unroll
            for (int of = 0; of < 4; of++)
                w[of] = *(const bf16x8*)(W_all + (size_t)(ot * 128 + wo * 64 + of * 16 + l15) * 256 + kt * 32 + lh * 8);
            #pragma unroll
            for (int nf = 0; nf < 4; nf++)
                #pragma unroll
                for (int of = 0; of < 4; of++)
                    acc[ot][nf][of] = __builtin_amdgcn_mfma_f32_16x16x32_bf16(a[nf], w[of], acc[ot][nf][of], 0, 0, 0);
        }
        __syncthreads();
        cur ^= 1;
    }

    #pragma unroll
    for (int ot = 0; ot < 3; ot++) {
        if (ot) __syncthreads();
        #pragma unroll
        for (int of = 0; of < 4; of++) {
            int ocol = wo * 64 + of * 16 + l15;
            float bias = b_all[ot * 128 + ocol];
            #pragma unroll
            for (int nf = 0; nf < 4; nf++)
                #pragma unroll
                for (int r = 0; r < 4; r++) {
                    int n  = wn * 64 + nf * 16 + lh * 4 + r;
                    int ch = (ocol >> 3) ^ (n & 15);
                    obuf[n * 128 + ch * 8 + (ocol & 7)] = f2bf(acc[ot][nf][of][r] + bias);
                }
        }
        __syncthreads();

        if (ot == 1) {
            #pragma unroll
            for (int p = 0; p < 8; p++) {
                int n  = wave * 4 + lh + p * 16;
                int ch = l15 ^ (n & 15);
                bf16x8 v = *(const bf16x8*)&obuf[n * 128 + ch * 8];
                *(bf16x8*)(OutT + ((size_t)b * 4096 + n0 + n) * 128 + l15 * 8) = v;
            }
        } else if (ot == 2) {
            const int wp = tid >> 3;
            const int cc = (tid & 7) * 16;
            short* kdst = Kmat + ((size_t)b * 1024 + ntile * 32 + wp) * 128 + cc;
            #pragma unroll
            for (int cblk = 0; cblk < 2; cblk++) {
                const int chunk = (cc >> 3) + cblk;
                float mx[8];
                #pragma unroll
                for (int j = 0; j < 8; j++) mx[j] = -1e30f;
                #pragma unroll
                for (int q4 = 0; q4 < 4; q4++) {
                    int n = (q4 >> 1) * 64 + 2 * wp + (q4 & 1);
                    bf16x8 v = *(const bf16x8*)&obuf[n * 128 + ((chunk ^ (n & 15)) * 8)];
                    #pragma unroll
                    for (int j = 0; j < 8; j++) mx[j] = fmaxf(mx[j], bf2f(v[j]));
                }
                bf16x8 vo;
                #pragma unroll
                for (int j = 0; j < 8; j++) vo[j] = f2bf(mx[j]);
                *(bf16x8*)(kdst + cblk * 8) = vo;
            }
        } else {
            const int c   = tid >> 1;
            const int wp0 = (tid & 1) * 16;
            const int chb = c >> 3, cl = c & 7;
            #pragma unroll
            for (int half = 0; half < 2; half++) {
                bf16x8 vo;
                #pragma unroll
                for (int j = 0; j < 8; j++) {
                    int wp = wp0 + half * 8 + j;
                    float mx = -1e30f;
                    #pragma unroll
                    for (int q4 = 0; q4 < 4; q4++) {
                        int n = (q4 >> 1) * 64 + 2 * wp + (q4 & 1);
                        mx = fmaxf(mx, bf2f(obuf[n * 128 + ((chb ^ (n & 15)) * 8) + cl]));
                    }
                    vo[j] = f2bf(mx);
                }
                *(bf16x8*)(Vmat + ((size_t)b * 128 + c) * 1024 + ntile * 32 + wp0 + half * 8) = vo;
            }
        }
    }
}

// ---------------- K3: flash attention, 8 waves x 32 q-rows, m-split 2, P in dead-K ----
__global__ __launch_bounds__(512) void k3_attn(const short* __restrict__ OutT,
        const short* __restrict__ Kmat, const short* __restrict__ Vmat,
        const short* __restrict__ Ww16, const float* __restrict__ bw,
        short* __restrict__ wy) {
    __shared__ short smem[65536];       // 128 KB
    const int bid = blockIdx.x;         // 256
    const int b   = bid & 7;
    const int nt  = bid >> 3;           // 32 tiles of 128 rows
    const int tid = threadIdx.x;
    const int lane = tid & 63;
    const int wave = tid >> 6;          // 0..7
    const int half = wave >> 2;
    const int wl   = wave & 3;
    const int l15 = lane & 15, lh = lane >> 4;
    const int nblk = nt * 128;
    const int n0 = nblk + wl * 32;
    const int mbase = half * 512;

    const short* Kb = Kmat + (size_t)b * 1024 * 128;
    const short* Vb = Vmat + (size_t)b * 128 * 1024;
    short* const sKh = smem + half * 16384;           // [2 dbuf][64*128]
    short* const sVh = smem + 32768 + half * 16384;   // [2 dbuf][128*64]

    auto STAGE = [&](int t, int bufi) {
        const int m0 = mbase + t * 64;
        #pragma unroll
        for (int i = 0; i < 4; i++) {
            const int segb = (i * 4 + wl) * 64;
            const int rowK = (segb >> 4) + (lane >> 4);
            const int chkK = lane & 15;
            gld16(Kb + (size_t)(m0 + rowK) * 128 + ((chkK ^ (rowK & 15)) << 3),
                  sKh + bufi * 8192 + segb * 8);
            const int rowV = (segb >> 3) + (lane >> 3);
            const int chkV = lane & 7;
            gld16(Vb + (size_t)rowV * 1024 + m0 + ((chkV ^ (rowV & 7)) << 3),
                  sVh + bufi * 8192 + segb * 8);
        }
    };

    bf16x8 q[2][4];
    #pragma unroll
    for (int nf = 0; nf < 2; nf++) {
        const short* qrow = OutT + ((size_t)b * 4096 + n0 + nf * 16 + l15) * 128;
        #pragma unroll
        for (int ks = 0; ks < 4; ks++)
            q[nf][ks] = *(const bf16x8*)(qrow + ks * 32 + lh * 8);
    }

    f32x4 y[2][8];
    #pragma unroll
    for (int nf = 0; nf < 2; nf++)
        #pragma unroll
        for (int cf = 0; cf < 8; cf++) y[nf][cf] = f32x4{0.f, 0.f, 0.f, 0.f};
    float mrun[2] = { -1e30f, -1e30f }, lrun[2] = { 0.f, 0.f };

    STAGE(0, 0);
    int cur = 0;

    for (int t = 0; t < 8; t++) {
        if (t < 7) {
            STAGE(t + 1, cur ^ 1);
            asm volatile("s_waitcnt vmcnt(8)" ::: "memory");
        } else {
            asm volatile("s_waitcnt vmcnt(0)" ::: "memory");
        }
        __builtin_amdgcn_s_barrier();
        __builtin_amdgcn_sched_barrier(0);

        const short* cK = sKh + cur * 8192;
        const short* cV = sVh + cur * 8192;

        f32x4 S[2][4];
        #pragma unroll
        for (int nf = 0; nf < 2; nf++)
            #pragma unroll
            for (int mf = 0; mf < 4; mf++) S[nf][mf] = f32x4{0.f, 0.f, 0.f, 0.f};
        #pragma unroll
        for (int ks = 0; ks < 4; ks++) {
            bf16x8 kf[4];
            #pragma unroll
            for (int mf = 0; mf < 4; mf++) {
                int mrow = mf * 16 + l15;
                int jj   = ks * 4 + lh;
                kf[mf] = *(const bf16x8*)&cK[mrow * 128 + ((jj ^ (mrow & 15)) << 3)];
            }
            __builtin_amdgcn_s_setprio(1);
            #pragma unroll
            for (int nf = 0; nf < 2; nf++)
                #pragma unroll
                for (int mf = 0; mf < 4; mf++)
                    S[nf][mf] = __builtin_amdgcn_mfma_f32_16x16x32_bf16(kf[mf], q[nf][ks], S[nf][mf], 0, 0, 0);
            __builtin_amdgcn_s_setprio(0);
        }

        float pm[2];
        #pragma unroll
        for (int nf = 0; nf < 2; nf++) {
            float v = S[nf][0][0];
            #pragma unroll
            for (int mf = 0; mf < 4; mf++)
                #pragma unroll
                for (int r = 0; r < 4; r++) v = fmaxf(v, S[nf][mf][r]);
            v = fmaxf(v, __shfl_xor(v, 16));
            v = fmaxf(v, __shfl_xor(v, 32));
            pm[nf] = v;
        }
        bool grow = (pm[0] > mrun[0] + 8.656f) | (pm[1] > mrun[1] + 8.656f);
        if (__any(grow)) {
            #pragma unroll
            for (int nf = 0; nf < 2; nf++) {
                float mnew  = fmaxf(mrun[nf], pm[nf]);
                float alpha = fexp2(mrun[nf] - mnew);
                mrun[nf] = mnew;
                lrun[nf] *= alpha;
                float aR[4];
                #pragma unroll
                for (int r = 0; r < 4; r++) aR[r] = __shfl(alpha, lh * 4 + r);
                #pragma unroll
                for (int cf = 0; cf < 8; cf++)
                    #pragma unroll
                    for (int r = 0; r < 4; r++) y[nf][cf][r] *= aR[r];
            }
        }
        #pragma unroll
        for (int nf = 0; nf < 2; nf++) {
            float rs = 0.f;
            #pragma unroll
            for (int mf = 0; mf < 4; mf++)
                #pragma unroll
                for (int r = 0; r < 4; r++) {
                    float p = fexp2(S[nf][mf][r] - mrun[nf]);
                    S[nf][mf][r] = p;
                    rs += p;
                }
            rs += __shfl_xor(rs, 16);
            rs += __shfl_xor(rs, 32);
            lrun[nf] += rs;
        }

        __builtin_amdgcn_sched_barrier(0);
        __builtin_amdgcn_s_barrier();

        short* const sPw = sKh + cur * 8192 + wl * 2048;
        #pragma unroll
        for (int nf = 0; nf < 2; nf++)
            #pragma unroll
            for (int mf = 0; mf < 4; mf++) {
                uint2 pk = { pk2bf(S[nf][mf][0], S[nf][mf][1]), pk2bf(S[nf][mf][2], S[nf][mf][3]) };
                int row = nf * 16 + l15;
                *(uint2*)&sPw[(row << 6) + (((mf * 4 + lh) ^ l15) << 2)] = pk;
            }

        #pragma unroll
        for (int ks2 = 0; ks2 < 2; ks2++) {
            int u0 = ks2 * 8 + lh * 2;
            bf16x8 pa[2];
            #pragma unroll
            for (int nf = 0; nf < 2; nf++) {
                int row = nf * 16 + l15;
                short4v lo = *(const short4v*)&sPw[(row << 6) + (((u0)     ^ l15) << 2)];
                short4v hi = *(const short4v*)&sPw[(row << 6) + (((u0 + 1) ^ l15) << 2)];
                pa[nf] = bf16x8{ lo.x, lo.y, lo.z, lo.w, hi.x, hi.y, hi.z, hi.w };
            }
            int jj = ks2 * 4 + lh;
            __builtin_amdgcn_s_setprio(1);
            #pragma unroll
            for (int cf = 0; cf < 8; cf++) {
                int crow = cf * 16 + l15;
                bf16x8 vf = *(const bf16x8*)&cV[crow * 64 + ((jj ^ (crow & 7)) << 3)];
                #pragma unroll
                for (int nf = 0; nf < 2; nf++)
                    y[nf][cf] = __builtin_amdgcn_mfma_f32_16x16x32_bf16(pa[nf], vf, y[nf][cf], 0, 0, 0);
            }
            __builtin_amdgcn_s_setprio(0);
        }

        __builtin_amdgcn_sched_barrier(0);
        __builtin_amdgcn_s_barrier();
        cur ^= 1;
    }

    // ---- merge halves ----
    float* const fsm = (float*)smem;                  // [128 rows][132]
    float* const fl  = fsm + 128 * 132;
    float* const fm  = fl + 128;
    if (half == 1) {
        #pragma unroll
        for (int nf = 0; nf < 2; nf++) {
            #pragma unroll
            for (int cf = 0; cf < 8; cf++)
                #pragma unroll
                for (int r = 0; r < 4; r++)
                    fsm[(wl * 32 + nf * 16 + lh * 4 + r) * 132 + cf * 16 + l15] = y[nf][cf][r];
            if (lh == 0) {
                fl[wl * 32 + nf * 16 + l15] = lrun[nf];
                fm[wl * 32 + nf * 16 + l15] = mrun[nf];
            }
        }
    }
    __syncthreads();
    if (half == 0) {
        #pragma unroll
        for (int nf = 0; nf < 2; nf++) {
            float m1 = fm[wl * 32 + nf * 16 + l15];
            float l1 = fl[wl * 32 + nf * 16 + l15];
            float mnew = fmaxf(mrun[nf], m1);
            float a0 = fexp2(mrun[nf] - mnew);
            float a1 = fexp2(m1 - mnew);
            float lnew = lrun[nf] * a0 + l1 * a1;
            float aR0[4], aR1[4], li[4];
            #pragma unroll
            for (int r = 0; r < 4; r++) {
                aR0[r] = __shfl(a0, lh * 4 + r);
                aR1[r] = __shfl(a1, lh * 4 + r);
                li[r]  = 1.f / __shfl(lnew, lh * 4 + r);
            }
            #pragma unroll
            for (int cf = 0; cf < 8; cf++)
                #pragma unroll
                for (int r = 0; r < 4; r++) {
                    float y1 = fsm[(wl * 32 + nf * 16 + lh * 4 + r) * 132 + cf * 16 + l15];
                    y[nf][cf][r] = (y[nf][cf][r] * aR0[r] + y1 * aR1[r]) * li[r];
                }
        }
    }
    __syncthreads();

    // ---- epilogue per 64-row half ----
    short* const Yt = smem;
    #pragma unroll
    for (int h = 0; h < 2; h++) {
        if (h) __syncthreads();
        if (half == 0 && (wl >> 1) == h) {
            #pragma unroll
            for (int nf = 0; nf < 2; nf++)
                #pragma unroll
                for (int cf = 0; cf < 8; cf++) {
                    int c = cf * 16 + l15;
                    #pragma unroll
                    for (int r = 0; r < 4; r++) {
                        int n = (wl & 1) * 32 + nf * 16 + lh * 4 + r;
                        Yt[n * 128 + (((c >> 3) ^ (n & 15)) << 3) + (c & 7)] = f2bf(y[nf][cf][r]);
                    }
                }
        }
        __syncthreads();

        bf16x8 by[4][4];
        #pragma unroll
        for (int nfi = 0; nfi < 4; nfi++)
            #pragma unroll
            for (int ks = 0; ks < 4; ks++) {
                int n  = nfi * 16 + l15;
                int kc = ks * 4 + lh;
                by[nfi][ks] = *(const bf16x8*)&Yt[n * 128 + ((kc ^ (n & 15)) << 3)];
            }

        short* const sOut = smem + 8192 + wave * 2304;
        const int obase = wave * 32;
        #pragma unroll
        for (int of = 0; of < 2; of++) {
            bf16x8 aw[4];
            #pragma unroll
            for (int ks = 0; ks < 4; ks++)
                aw[ks] = *(const bf16x8*)(Ww16 + (size_t)(obase + of * 16 + l15) * 128 + ks * 32 + lh * 8);
            #pragma unroll
            for (int nfi = 0; nfi < 4; nfi++) {
                f32x4 acc = f32x4{0.f, 0.f, 0.f, 0.f};
                #pragma unroll
                for (int ks = 0; ks < 4; ks++)
                    acc = __builtin_amdgcn_mfma_f32_16x16x32_bf16(aw[ks], by[nfi][ks], acc, 0, 0, 0);
                #pragma unroll
                for (int r = 0; r < 4; r++) {
                    int o_loc = of * 16 + lh * 4 + r;
                    sOut[o_loc * 72 + nfi * 16 + l15] = f2bf(acc[r] + bw[obase + o_loc]);
                }
            }
        }

        #pragma unroll
        for (int p = 0; p < 4; p++) {
            int o_loc = p * 8 + (lane >> 3);
            int n8    = (lane & 7) * 8;
            bf16x8 v = *(const bf16x8*)&sOut[o_loc * 72 + n8];
            *(bf16x8*)(wy + ((size_t)b * 256 + obase + o_loc) * 4096 + nblk + h * 64 + n8) = v;
        }
    }
}

// ---------------- K45: BN stats + apply + residual + global spatial max ----------------
__global__ __launch_bounds__(512) void k45_bnmax(const short* __restrict__ wy,
        const float* __restrict__ x,
        const float* __restrict__ gamma, const float* __restrict__ beta,
        float* __restrict__ outp) {
    const int o   = blockIdx.x;     // 256
    const int tid = threadIdx.x;    // 512
    const int lane = tid & 63;
    const int wave = tid >> 6;

    bf16x8 w8[8];
    float s = 0.f, s2 = 0.f;
    #pragma unroll
    for (int b = 0; b < 8; b++) {
        w8[b] = *(const bf16x8*)(wy + ((size_t)b * 256 + o) * 4096 + tid * 8);
        #pragma unroll
        for (int j = 0; j < 8; j++) {
            float f = bf2f(w8[b][j]);
            s += f; s2 += f * f;
        }
    }
    #pragma unroll
    for (int off = 1; off < 64; off <<= 1) { s += __shfl_xor(s, off); s2 += __shfl_xor(s2, off); }
    __shared__ float sred[8][2];
    if (lane == 0) { sred[wave][0] = s; sred[wave][1] = s2; }
    __syncthreads();
    s = 0.f; s2 = 0.f;
    #pragma unroll
    for (int wv = 0; wv < 8; wv++) { s += sred[wv][0]; s2 += sred[wv][1]; }
    float mean = s * (1.f / 32768.f);
    float var  = s2 * (1.f / 32768.f) - mean * mean;
    float rstd = rsqrtf(var + 1e-5f);
    float A = rstd * gamma[o];
    float B = beta[o] - mean * A;

    float mx[8];
    #pragma unroll
    for (int b = 0; b < 8; b++) {
        const float* px = x + ((size_t)b * 256 + o) * 4096 + tid * 8;
        float4 xa = *(const float4*)px;
        float4 xb = *(const float4*)(px + 4);
        float m = bf2f(w8[b][0]) * A + B + xa.x;
        m = fmaxf(m, bf2f(w8[b][1]) * A + B + xa.y);
        m = fmaxf(m, bf2f(w8[b][2]) * A + B + xa.z);
        m = fmaxf(m, bf2f(w8[b][3]) * A + B + xa.w);
        m = fmaxf(m, bf2f(w8[b][4]) * A + B + xb.x);
        m = fmaxf(m, bf2f(w8[b][5]) * A + B + xb.y);
        m = fmaxf(m, bf2f(w8[b][6]) * A + B + xb.z);
        m = fmaxf(m, bf2f(w8[b][7]) * A + B + xb.w);
        mx[b] = m;
    }
    #pragma unroll
    for (int b = 0; b < 8; b++)
        #pragma unroll
        for (int off = 1; off < 64; off <<= 1) mx[b] = fmaxf(mx[b], __shfl_xor(mx[b], off));
    __shared__ float mred[8][8];
    if (lane == 0) {
        #pragma unroll
        for (int b = 0; b < 8; b++) mred[wave][b] = mx[b];
    }
    __syncthreads();
    if (tid < 8) {
        float m = mred[0][tid];
        #pragma unroll
        for (int wv = 1; wv < 8; wv++) m = fmaxf(m, mred[wv][tid]);
        outp[tid * 256 + o] = m;
    }
}

extern "C" void kernel_launch(void* const* d_in, const int* in_sizes, int n_in,
                              void* d_out, int out_size, void* d_ws, size_t ws_size,
                              hipStream_t stream) {
    const float* x     = (const float*)d_in[0];
    const float* Wg    = (const float*)d_in[1];
    const float* bg    = (const float*)d_in[2];
    const float* Wt    = (const float*)d_in[3];
    const float* bt    = (const float*)d_in[4];
    const float* Wp    = (const float*)d_in[5];
    const float* bp    = (const float*)d_in[6];
    const float* Ww    = (const float*)d_in[7];
    const float* bw    = (const float*)d_in[8];
    const float* gamma = (const float*)d_in[9];
    const float* beta  = (const float*)d_in[10];
    float* outp = (float*)d_out;

    char* ws = (char*)d_ws;
    size_t off = 0;
    auto alloc = [&](size_t bytes) -> void* {
        void* p = ws + off;
        off = (off + bytes + 255) & ~(size_t)255;
        return p;
    };
    short* W_all = (short*)alloc((size_t)384 * 256 * 2);
    short* Ww16  = (short*)alloc((size_t)256 * 128 * 2);
    float* b_all = (float*)alloc((size_t)384 * 4);
    short* OutT  = (short*)alloc((size_t)8 * 4096 * 128 * 2);
    short* Kmat  = (short*)alloc((size_t)8 * 1024 * 128 * 2);
    short* Vmat  = (short*)alloc((size_t)8 * 128 * 1024 * 2);
    short* wy    = (short*)alloc((size_t)8 * 256 * 4096 * 2);

    k0_prep<<<512, 256, 0, stream>>>(Wg, Wt, Wp, bg, bt, bp, Ww, W_all, Ww16, b_all);
    k1_conv<<<dim3(32, 8), 256, 0, stream>>>(x, W_all, b_all, OutT, Kmat, Vmat);
    k3_attn<<<256, 512, 0, stream>>>(OutT, Kmat, Vmat, Ww16, bw, wy);
    k45_bnmax<<<256, 512, 0, stream>>>(wy, x, gamma, beta, outp);
}